// Round 7
// baseline (35649.799 us; speedup 1.0000x reference)
//
#include <hip/hip_runtime.h>
#include <hip/hip_bf16.h>
#include <hip/hip_cooperative_groups.h>

#define HID   1024
#define BATCH 512
#define SEQ   256
#define OUTD  64
#define NGATE 4096
#define NBLK  256
#define NTHR  512
#define NPH   512            // gbar slots: 2 per timestep
#define NLB   520            // lbar slots: 1 prologue + 2 per timestep
#define HSZ   (512 * 1024)   // elems per h slab [512][1024] (single, no parity)

typedef __attribute__((ext_vector_type(8))) short bf16x8;
typedef __attribute__((ext_vector_type(4))) float f32x4;
typedef __attribute__((ext_vector_type(16))) float f32x16;
typedef __attribute__((ext_vector_type(4))) unsigned u32x4;
typedef unsigned short u16;
typedef unsigned long long u64;

// LDS: pld [8 kq][64 m][32 n] f32 (64 KB) + bcast 256 B. No operand staging.
#define LDS_BYTES (65536 + 256)

#define AQ __ATOMIC_RELAXED, __HIP_MEMORY_SCOPE_AGENT

__device__ __forceinline__ u16 f2bf(float v) {
  union { float f; unsigned u; } u; u.f = v;
  unsigned r = u.u + 0x7fffu + ((u.u >> 16) & 1u);
  return (u16)(r >> 16);
}
__device__ __forceinline__ float bf2f(u16 b) {
  union { unsigned u; float f; } u; u.u = ((unsigned)b) << 16;
  return u.f;
}
__device__ __forceinline__ float sigf(float x) { return 1.0f / (1.0f + __expf(-x)); }
__device__ __forceinline__ float tanh_fast(float x) {
  float ax = fabsf(x);
  float e = __expf(-2.0f * ax);
  return copysignf((1.0f - e) / (1.0f + e), x);
}

// agent-scope relaxed (write-through / cache-bypass to MALL). r0-r6 proven.
__device__ __forceinline__ void st_dev32(u16* p, unsigned v) {
  __hip_atomic_store((unsigned*)p, v, AQ);
}
__device__ __forceinline__ u64 ld_dev64(const u16* p) {
  return __hip_atomic_load((const u64*)p, AQ);
}

// 16B cache-bypass load (L1+L2 bypass -> MALL). Result NOT ready until the
// following s_waitcnt asm that ties the value registers (rule: waitcnt asm
// must data-depend on the loads + sched_barrier to stop hoisting).
#define LD_BYP16(dst, addr) \
  asm volatile("global_load_dwordx4 %0, %1, off sc0 sc1" \
               : "=v"(dst) : "v"(addr) : "memory")

// W frag index for the register-resident layout (r2-r6 verified).
__device__ __forceinline__ size_t fidx(int np, int k) {
  int s = np >> 5, nl = np & 31;
  int c = k >> 8;
  int kq = (k >> 5) & 7;
  int kfs = (k >> 4) & 1;
  int h = (k >> 3) & 1;
  int e = k & 7;
  int f = c * 2 + kfs;
  return ((size_t)(s * 8 + kq) * 16 + f) * 512 + (h * 32 + nl) * 8 + e;
}

// ---------------- prepass kernels (r2-r6 verified) ----------------

__global__ void k_build_w0f(const float* __restrict__ Whh0, const float* __restrict__ Wih0,
                            const float* __restrict__ fcw, u16* __restrict__ w0f) {
  int np = blockIdx.x;
  int j = np >> 2, gg = np & 3;
  int orig = gg * 1024 + j;
  int tid = threadIdx.x;
  __shared__ float wrow[64];
  if (tid < 64) wrow[tid] = Wih0[orig * 64 + tid];
  __syncthreads();
  for (int k = tid; k < 1024; k += 256) {
    w0f[fidx(np, k)] = f2bf(Whh0[(size_t)orig * 1024 + k]);
    float acc = 0.f;
#pragma unroll
    for (int o = 0; o < 64; ++o) acc += wrow[o] * fcw[o * 1024 + k];
    w0f[fidx(np, 1024 + k)] = f2bf(acc);   // folded Wih0 @ fc_out
  }
}

__global__ void k_build_w1f(const float* __restrict__ Wih1, const float* __restrict__ Whh1,
                            u16* __restrict__ w1f) {
  int np = blockIdx.x;
  int j = np >> 2, gg = np & 3;
  int orig = gg * 1024 + j;
  int tid = threadIdx.x;
  for (int k = tid; k < 1024; k += 256) {
    w1f[fidx(np, k)]        = f2bf(Wih1[(size_t)orig * 1024 + k]);
    w1f[fidx(np, 1024 + k)] = f2bf(Whh1[(size_t)orig * 1024 + k]);
  }
}

__global__ void k_build_bias(const float* bih0, const float* bhh0,
                             const float* bih1, const float* bhh1,
                             const float* Wih0, const float* fcb,
                             float* bias0b, float* bias0x, float* bias1) {
  int np = blockIdx.x * 256 + threadIdx.x;
  if (np >= NGATE) return;
  int j = np >> 2, gg = np & 3;
  int orig = gg * 1024 + j;
  bias0b[np] = bih0[orig] + bhh0[orig];
  bias1[np]  = bih1[orig] + bhh1[orig];
  float acc = 0.f;
#pragma unroll
  for (int o = 0; o < 64; ++o) acc += Wih0[orig * 64 + o] * fcb[o];
  bias0x[np] = acc;   // fc_out bias routed through W_ih0 (valid only t>=1; x(0)=0)
}

__global__ void k_fcwb(const float* __restrict__ fcw, u16* __restrict__ fcwb) {
  int idx = blockIdx.x * 256 + threadIdx.x;  // 65536
  fcwb[idx] = f2bf(fcw[idx]);
}

// writes h0_init -> xg0 slab, h1_init -> xg1 slab
__global__ void k_init(const float* __restrict__ zs, const float* __restrict__ zk,
                       const float* __restrict__ fiw, const float* __restrict__ fib,
                       u16* __restrict__ xg0, u16* __restrict__ xg1) {
  int r = blockIdx.x;
  int tid = threadIdx.x;
  __shared__ float z[256];
  if (tid < 128) z[tid] = zs[r * 128 + tid];
  else           z[tid] = zk[r * 128 + (tid - 128)];
  __syncthreads();
  for (int c = tid; c < 2048; c += 256) {
    float acc = fib[c];
    const float* w = fiw + (size_t)c * 256;
#pragma unroll 8
    for (int k = 0; k < 256; ++k) acc += z[k] * w[k];
    int l = (r >= 256) ? 1 : 0;
    int b = 2 * (r - l * 256) + (c >> 10);
    int h = c & 1023;
    u16 v = f2bf(acc);
    if (l == 0) xg0[(size_t)b * 1024 + h] = v;
    else        xg1[(size_t)b * 1024 + h] = v;
  }
}

// ---------------- main cooperative kernel ----------------

struct Params {
  const u16* w0f;        // frag-ordered, register-resident after prologue
  const u16* w1f;
  const float* bias0b;
  const float* bias0x;
  const float* bias1;
  u16* xg0;              // [512][1024] h0 slab (MALL write-through, single)
  u16* xg1;              // [512][1024] h1 slab
  u16* scr;              // [8 xcd][2 grp][256][2048] per-XCD operand scratch (L2-local)
  const u16* fcwb;       // [64][1024] bf16
  const float* fcb;
  float* out;            // [512][256][64]
  unsigned* igctr;       // init barrier counter
  unsigned* rkg;         // [8 xcd][2 grp] rank counters
  unsigned* gcnt;        // [2] group block totals
  unsigned* sctr;        // [16][NLB] fill-ready counters  (per xcd,grp)
  unsigned* axg;         // [16][NPH] gbar arrival         (per xcd,grp)
  unsigned* rls;         // [16][NPH] gbar release flags   (per xcd,grp)
  unsigned* gctr;        // [2][NPH]  gbar group-combine   (per grp)
};

__global__ __launch_bounds__(NTHR, 2)
void k_lstm(Params p) {
  extern __shared__ char smem[];
  float* pld = (float*)smem;                          // [8 kq][64 m][32 n] f32
  volatile unsigned* bc = (volatile unsigned*)(smem + 65536);

  const int blk = blockIdx.x, tid = threadIdx.x;
  const int lane = tid & 63, wave = tid >> 6;   // wave id = kq (K-slice)
  const int x8 = blk & 7;
  const int g = x8 >> 2;                        // batch group 0..1
  const int s = (blk >> 3) * 4 + (x8 & 3);      // gate-slab 0..127 (np 32s..32s+32)
  const int nl = lane & 31, hh = lane >> 5;

  unsigned xcd;
  asm("s_getreg_b32 %0, hwreg(HW_REG_XCC_ID, 0, 32)" : "=s"(xcd));
  xcd &= 7;

  // ---- rank discovery + one global init barrier (agent atomics only) ----
  if (tid == 0) {
    unsigned rg = __hip_atomic_fetch_add(&p.rkg[xcd * 2 + g], 1u, AQ);
    __hip_atomic_fetch_add(&p.gcnt[g], 1u, AQ);
    __hip_atomic_fetch_add(p.igctr, 1u, AQ);
    while (__hip_atomic_load(p.igctr, AQ) < (unsigned)NBLK)
      __builtin_amdgcn_s_sleep(2);
    bc[0] = rg;
    bc[1] = __hip_atomic_load(&p.rkg[xcd * 2 + g], AQ);
    bc[2] = __hip_atomic_load(&p.gcnt[g], AQ);
  }
  __syncthreads();
  const unsigned rg_   = bc[0];   // my rank within (xcd, group)
  const unsigned ng_   = bc[1];   // blocks of my group on this XCD (>=1)
  const unsigned ngrp_ = bc[2];   // total blocks of my group
  const bool lead = (rg_ == 0);
  __syncthreads();

  // ---- load W into registers: zero W fetch for all 512 phases (r2-proven) ----
  bf16x8 w0r[16], w1r[16];
  {
    const u16* W0p = p.w0f + (size_t)(s * 8 + wave) * 8192 + (hh * 32 + nl) * 8;
    const u16* W1p = p.w1f + (size_t)(s * 8 + wave) * 8192 + (hh * 32 + nl) * 8;
#pragma unroll
    for (int f = 0; f < 16; ++f) {
      w0r[f] = *(const bf16x8*)(W0p + f * 512);
      w1r[f] = *(const bf16x8*)(W1p + f * 512);
    }
  }

  // cell assignment: one (row-in-pass, hidden-unit) per lane
  const int cr_ = tid >> 3, cj = tid & 7;
  const int npb = s * 32 + 4 * cj;
  const f32x4 b0 = *(const f32x4*)&p.bias0b[npb];
  const f32x4 bx = *(const f32x4*)&p.bias0x[npb];
  const f32x4 b1 = *(const f32x4*)&p.bias1[npb];
  const int jcol = s * 8 + cj;

  float c0s[4] = {0, 0, 0, 0}, c1s[4] = {0, 0, 0, 0};

  u16* scrg = p.scr + (size_t)(xcd * 2 + g) * 256 * 2048;  // (XCD,group) scratch

  // ---- group-scoped hierarchical barrier (r6-proven, no sc1 fence) ----
  auto gbar = [&](int ph) {
    __syncthreads();   // vmcnt(0) drain -> h write-through stores durable
    if (tid == 0) {
      unsigned* ax = &p.axg[(xcd * 2 + g) * NPH + ph];
      __hip_atomic_fetch_add(ax, 1u, AQ);
      if (lead) {
        while (__hip_atomic_load(ax, AQ) < ng_) __builtin_amdgcn_s_sleep(1);
        unsigned* gc = &p.gctr[g * NPH + ph];
        __hip_atomic_fetch_add(gc, ng_, AQ);
        while (__hip_atomic_load(gc, AQ) < ngrp_) __builtin_amdgcn_s_sleep(1);
        __hip_atomic_store(&p.rls[(xcd * 2 + g) * NPH + ph], 1u, AQ);
      } else {
        while (!__hip_atomic_load(&p.rls[(xcd * 2 + g) * NPH + ph], AQ))
          __builtin_amdgcn_s_sleep(1);
      }
    }
    __syncthreads();
  };

  // XCD-local fill-ready barrier + private-L1 flash (r3/r6-proven cheap)
  auto lbar = [&](int slot) {
    __syncthreads();   // drain fill stores into own L2
    if (tid == 0) {
      unsigned* c = &p.sctr[(xcd * 2 + g) * NLB + slot];
      __hip_atomic_fetch_add(c, 1u, AQ);
      while (__hip_atomic_load(c, AQ) < ng_) __builtin_amdgcn_s_sleep(1);
    }
    __syncthreads();
    asm volatile("buffer_inv sc0\n\ts_waitcnt vmcnt(0)" ::: "memory");
  };

  // HALF-slab fill: update scratch cols [off,off+1024) for my (xcd,g)'s rows
  // from slab src [512][1024]. 16B bypass loads, 4 chunks in flight -> one
  // MALL latency instead of 8-16 serial round-trips. Scratch halves persist
  // across phases, so each fill moves only the half just produced (0.5 MB/XCD).
  auto fill_half = [&](const u16* src, int off, bool zero) {
    const int rsub = tid >> 7;          // 0..3 row within 4-row chunk
    const int csub = (tid & 127) * 8;   // col (elems)
    for (int c0 = (int)rg_; c0 < 64; c0 += 4 * (int)ng_) {
      const int c1 = c0 + (int)ng_, c2 = c0 + 2 * (int)ng_, c3 = c0 + 3 * (int)ng_;
      u32x4 v0 = {0,0,0,0}, v1 = {0,0,0,0}, v2 = {0,0,0,0}, v3 = {0,0,0,0};
      if (!zero) {
        LD_BYP16(v0, src + (size_t)(g * 256 + c0 * 4 + rsub) * 1024 + csub);
        if (c1 < 64) LD_BYP16(v1, src + (size_t)(g * 256 + c1 * 4 + rsub) * 1024 + csub);
        if (c2 < 64) LD_BYP16(v2, src + (size_t)(g * 256 + c2 * 4 + rsub) * 1024 + csub);
        if (c3 < 64) LD_BYP16(v3, src + (size_t)(g * 256 + c3 * 4 + rsub) * 1024 + csub);
        asm volatile("s_waitcnt vmcnt(0)"
                     : "+v"(v0), "+v"(v1), "+v"(v2), "+v"(v3) :: "memory");
        __builtin_amdgcn_sched_barrier(0);
      }
      *(u32x4*)(scrg + (size_t)(c0 * 4 + rsub) * 2048 + off + csub) = v0;
      if (c1 < 64) *(u32x4*)(scrg + (size_t)(c1 * 4 + rsub) * 2048 + off + csub) = v1;
      if (c2 < 64) *(u32x4*)(scrg + (size_t)(c2 * 4 + rsub) * 2048 + off + csub) = v2;
      if (c3 < 64) *(u32x4*)(scrg + (size_t)(c3 * 4 + rsub) * 2048 + off + csub) = v3;
    }
  };

  // out(tq) for this block's 2 batch rows; h1(tq) = scratch cols [1024,2048)
  auto out_proj_s = [&](int tq) {
    const int o = tid >> 3, ks = tid & 7;
#pragma unroll
    for (int rr = 0; rr < 2; ++rr) {
      const int rl = 2 * s + rr;
      const u16* hp = scrg + (size_t)rl * 2048 + 1024 + ks * 128;
      const u16* wp = p.fcwb + (size_t)o * 1024 + ks * 128;
      float a = 0.f;
#pragma unroll
      for (int kk = 0; kk < 128; kk += 8) {
        bf16x8 hv = *(const bf16x8*)(hp + kk);
        bf16x8 wv = *(const bf16x8*)(wp + kk);
#pragma unroll
        for (int jj = 0; jj < 8; ++jj)
          a += bf2f(((u16*)&hv)[jj]) * bf2f(((u16*)&wv)[jj]);
      }
      a += __shfl_xor(a, 1);
      a += __shfl_xor(a, 2);
      a += __shfl_xor(a, 4);
      if (ks == 0)
        p.out[((size_t)(g * 256 + rl) * SEQ + tq) * OUTD + o] = a + p.fcb[o];
    }
  };

  // one layer-phase: 4 passes of 64 rows. MFMA A-frags load DIRECTLY from
  // L2-local scratch through L1 (no LDS operand staging, no K-loop barriers,
  // no XOR swizzle). Each 128B scratch line is fully consumed by a wave pair
  // on this CU. Then 8-way K reduce via pld LDS, fused cell, h publish.
  auto phase = [&](bf16x8 (&wr)[16], u16* dst,
                   const f32x4& bb, const f32x4& bxx, bool ubx, float (&cs)[4]) {
#pragma unroll
    for (int pass = 0; pass < 4; ++pass) {
      const u16* b0p = scrg + (size_t)(pass * 64 + nl) * 2048 + wave * 32 + hh * 8;
      const u16* b1p = b0p + (size_t)32 * 2048;
      f32x16 acc0, acc1;
#pragma unroll
      for (int z = 0; z < 16; ++z) { acc0[z] = 0.f; acc1[z] = 0.f; }
#pragma unroll
      for (int c = 0; c < 8; ++c) {
        const bf16x8 f0 = *(const bf16x8*)(b0p + c * 256);
        const bf16x8 f1 = *(const bf16x8*)(b0p + c * 256 + 16);
        const bf16x8 f2 = *(const bf16x8*)(b1p + c * 256);
        const bf16x8 f3 = *(const bf16x8*)(b1p + c * 256 + 16);
        acc0 = __builtin_amdgcn_mfma_f32_32x32x16_bf16(f0, wr[2 * c],     acc0, 0, 0, 0);
        acc0 = __builtin_amdgcn_mfma_f32_32x32x16_bf16(f1, wr[2 * c + 1], acc0, 0, 0, 0);
        acc1 = __builtin_amdgcn_mfma_f32_32x32x16_bf16(f2, wr[2 * c],     acc1, 0, 0, 0);
        acc1 = __builtin_amdgcn_mfma_f32_32x32x16_bf16(f3, wr[2 * c + 1], acc1, 0, 0, 0);
      }
      // K-partials to LDS (C/D: col=lane&31, row=(reg&3)+8*(reg>>2)+4*(lane>>5))
#pragma unroll
      for (int r16 = 0; r16 < 16; ++r16) {
        const int row0 = (r16 & 3) + 8 * (r16 >> 2) + 4 * hh;
        pld[(wave * 64 + row0) * 32 + nl] = acc0[r16];
        pld[(wave * 64 + 32 + row0) * 32 + nl] = acc1[r16];
      }
      __syncthreads();
      // reduce 8 partials + fused cell for this lane's (row, hidden unit)
      f32x4 gs = {0.f, 0.f, 0.f, 0.f};
#pragma unroll
      for (int q = 0; q < 8; ++q) {
        const f32x4 v = *(const f32x4*)&pld[(q * 64 + cr_) * 32 + 4 * cj];
        gs[0] += v[0]; gs[1] += v[1]; gs[2] += v[2]; gs[3] += v[3];
      }
      const float gi = gs[0] + bb[0] + (ubx ? bxx[0] : 0.f);
      const float gf = gs[1] + bb[1] + (ubx ? bxx[1] : 0.f);
      const float gg = gs[2] + bb[2] + (ubx ? bxx[2] : 0.f);
      const float go = gs[3] + bb[3] + (ubx ? bxx[3] : 0.f);
      const float iv = sigf(gi), fv = sigf(gf), gv = tanh_fast(gg), ov = sigf(go);
      const float cnew = fv * cs[pass] + iv * gv;
      cs[pass] = cnew;
      const float hnew = ov * tanh_fast(cnew);
      const u16 hv = f2bf(hnew);
      const unsigned other = __shfl_xor((unsigned)hv, 1);
      if (!(tid & 1)) {   // even lane packs (jcol, jcol+1) -> one u32 write-through
        const unsigned pairv = (unsigned)hv | (other << 16);
        st_dev32(dst + (size_t)(g * 256 + pass * 64 + cr_) * 1024 + jcol, pairv);
      }
      __syncthreads();   // pld reuse in next pass
    }
  };

  // prologue: scratch = [h0_init | 0]  (x(0)=0)
  fill_half(p.xg0, 0, false);
  fill_half(nullptr, 1024, true);
  lbar(0);

  for (int t = 0; t < SEQ; ++t) {
    // ---- phase A: operand [h0(t-1) | h1(t-1)] -> h0(t) -> xg0 ----
    if (t > 0) out_proj_s(t - 1);                 // h1(t-1) in scratch hi
    phase(w0r, p.xg0, b0, bx, t > 0, c0s);
    gbar(2 * t);
    // ---- fill B: lo <- h0(t); at t=0 also hi <- h1_init (r5-bug case) ----
    fill_half(p.xg0, 0, false);
    if (t == 0) fill_half(p.xg1, 1024, false);
    lbar(2 * t + 1);
    // ---- phase B: operand [h0(t) | h1(t-1)] -> h1(t) -> xg1 ----
    phase(w1r, p.xg1, b1, b1, false, c1s);
    gbar(2 * t + 1);
    // ---- fill A(t+1): hi <- h1(t); lo (h0(t)) already in scratch ----
    if (t + 1 < SEQ) {
      fill_half(p.xg1, 1024, false);
      lbar(2 * t + 2);
    }
  }
  // final out(SEQ-1): h1(255) in xg1, via bypass loads
  {
    const int o = tid >> 3, ks = tid & 7;
#pragma unroll
    for (int rr = 0; rr < 2; ++rr) {
      const int r = g * 256 + 2 * s + rr;
      const u16* hp = p.xg1 + (size_t)r * 1024 + ks * 128;
      const u16* wp = p.fcwb + (size_t)o * 1024 + ks * 128;
      float a = 0.f;
      for (int kk = 0; kk < 128; kk += 4) {
        u64 hv = ld_dev64(hp + kk);
        a += bf2f((u16)hv)         * bf2f(wp[kk]);
        a += bf2f((u16)(hv >> 16)) * bf2f(wp[kk + 1]);
        a += bf2f((u16)(hv >> 32)) * bf2f(wp[kk + 2]);
        a += bf2f((u16)(hv >> 48)) * bf2f(wp[kk + 3]);
      }
      a += __shfl_xor(a, 1);
      a += __shfl_xor(a, 2);
      a += __shfl_xor(a, 4);
      if (ks == 0)
        p.out[((size_t)r * SEQ + (SEQ - 1)) * OUTD + o] = a + p.fcb[o];
    }
  }
}

// ---------------- launch ----------------

extern "C" void kernel_launch(void* const* d_in, const int* in_sizes, int n_in,
                              void* d_out, int out_size, void* d_ws, size_t ws_size,
                              hipStream_t stream) {
  const float* zs   = (const float*)d_in[0];
  const float* zk   = (const float*)d_in[1];
  const float* fiw  = (const float*)d_in[2];
  const float* fib  = (const float*)d_in[3];
  const float* Wih0 = (const float*)d_in[4];
  const float* Whh0 = (const float*)d_in[5];
  const float* bih0 = (const float*)d_in[6];
  const float* bhh0 = (const float*)d_in[7];
  const float* Wih1 = (const float*)d_in[8];
  const float* Whh1 = (const float*)d_in[9];
  const float* bih1 = (const float*)d_in[10];
  const float* bhh1 = (const float*)d_in[11];
  const float* fcw  = (const float*)d_in[12];
  const float* fcb  = (const float*)d_in[13];
  float* out = (float*)d_out;

  char* ws = (char*)d_ws;
  size_t off = 0;
  auto alloc = [&](size_t bytes) -> char* {
    char* pp = ws + off;
    off += (bytes + 255) & ~(size_t)255;
    return pp;
  };
  u16* w0f  = (u16*)alloc((size_t)NGATE * 2048 * 2);        // 16 MB
  u16* w1f  = (u16*)alloc((size_t)NGATE * 2048 * 2);        // 16 MB
  u16* xg0  = (u16*)alloc((size_t)HSZ * 2);                 // 1 MB
  u16* xg1  = (u16*)alloc((size_t)HSZ * 2);                 // 1 MB
  u16* scr  = (u16*)alloc((size_t)8 * 2 * 256 * 2048 * 2);  // 16 MB
  u16* fcwb = (u16*)alloc((size_t)OUTD * HID * 2);
  float* bias0b = (float*)alloc(NGATE * 4);
  float* bias0x = (float*)alloc(NGATE * 4);
  float* bias1  = (float*)alloc(NGATE * 4);
  unsigned* igctr = (unsigned*)alloc(256);
  unsigned* rkg   = (unsigned*)alloc(16 * 4);
  unsigned* gcnt  = (unsigned*)alloc(2 * 4);
  unsigned* sctr  = (unsigned*)alloc((size_t)16 * NLB * 4);
  unsigned* axg   = (unsigned*)alloc((size_t)16 * NPH * 4);
  unsigned* rls   = (unsigned*)alloc((size_t)16 * NPH * 4);
  unsigned* gctr  = (unsigned*)alloc((size_t)2 * NPH * 4);

  hipMemsetAsync(igctr, 0, 256, stream);
  hipMemsetAsync(rkg, 0, 16 * 4, stream);
  hipMemsetAsync(gcnt, 0, 2 * 4, stream);
  hipMemsetAsync(sctr, 0, (size_t)16 * NLB * 4, stream);
  hipMemsetAsync(axg, 0, (size_t)16 * NPH * 4, stream);
  hipMemsetAsync(rls, 0, (size_t)16 * NPH * 4, stream);
  hipMemsetAsync(gctr, 0, (size_t)2 * NPH * 4, stream);

  hipLaunchKernelGGL(k_build_w0f, dim3(NGATE), dim3(256), 0, stream, Whh0, Wih0, fcw, w0f);
  hipLaunchKernelGGL(k_build_w1f, dim3(NGATE), dim3(256), 0, stream, Wih1, Whh1, w1f);
  hipLaunchKernelGGL(k_build_bias, dim3(16), dim3(256), 0, stream,
                     bih0, bhh0, bih1, bhh1, Wih0, fcb, bias0b, bias0x, bias1);
  hipLaunchKernelGGL(k_fcwb, dim3(256), dim3(256), 0, stream, fcw, fcwb);
  hipLaunchKernelGGL(k_init, dim3(BATCH), dim3(256), 0, stream, zs, zk, fiw, fib, xg0, xg1);

  Params prm;
  prm.w0f = w0f; prm.w1f = w1f;
  prm.bias0b = bias0b; prm.bias0x = bias0x; prm.bias1 = bias1;
  prm.xg0 = xg0; prm.xg1 = xg1; prm.scr = scr;
  prm.fcwb = fcwb; prm.fcb = fcb; prm.out = out;
  prm.igctr = igctr; prm.rkg = rkg; prm.gcnt = gcnt;
  prm.sctr = sctr; prm.axg = axg; prm.rls = rls; prm.gctr = gctr;

  hipFuncSetAttribute((const void*)k_lstm, hipFuncAttributeMaxDynamicSharedMemorySize, LDS_BYTES);
  void* args[] = { &prm };
  hipLaunchCooperativeKernel((void*)k_lstm, dim3(NBLK), dim3(NTHR), args, LDS_BYTES, stream);
}

// Round 8
// 25552.765 us; speedup vs baseline: 1.3951x; 1.3951x over previous
//
#include <hip/hip_runtime.h>
#include <hip/hip_bf16.h>
#include <hip/hip_cooperative_groups.h>

#define HID   1024
#define BATCH 512
#define SEQ   256
#define OUTD  64
#define NGATE 4096
#define NBLK  256
#define NTHR  512
#define NPH   512            // gbar slots: 2 per timestep
#define NLB   520            // lbar slots: 1 prologue + 2 per timestep
#define HSZ   (512 * 1024)   // elems per h slab [512][1024] (single, no parity)

typedef __attribute__((ext_vector_type(8))) short bf16x8;
typedef __attribute__((ext_vector_type(4))) float f32x4;
typedef __attribute__((ext_vector_type(16))) float f32x16;
typedef unsigned short u16;
typedef unsigned long long u64;

// LDS: win0/win1 [64 rows][256 k] bf16 (32 KB each, XOR-swizzled, r6-proven),
//      pld [8 kq][64 m][32 n] f32 (64 KB), bcast 256 B
#define WIN_BYTES 32768
#define LDS_BYTES (2 * WIN_BYTES + 65536 + 256)

#define AQ __ATOMIC_RELAXED, __HIP_MEMORY_SCOPE_AGENT

__device__ __forceinline__ u16 f2bf(float v) {
  union { float f; unsigned u; } u; u.f = v;
  unsigned r = u.u + 0x7fffu + ((u.u >> 16) & 1u);
  return (u16)(r >> 16);
}
__device__ __forceinline__ float bf2f(u16 b) {
  union { unsigned u; float f; } u; u.u = ((unsigned)b) << 16;
  return u.f;
}
__device__ __forceinline__ float sigf(float x) { return 1.0f / (1.0f + __expf(-x)); }
__device__ __forceinline__ float tanh_fast(float x) {
  float ax = fabsf(x);
  float e = __expf(-2.0f * ax);
  return copysignf((1.0f - e) / (1.0f + e), x);
}

// agent-scope relaxed (write-through / cache-bypass to MALL). r0-r7 proven.
__device__ __forceinline__ void st_dev32(u16* p, unsigned v) {
  __hip_atomic_store((unsigned*)p, v, AQ);
}
__device__ __forceinline__ u64 ld_dev64(const u16* p) {
  return __hip_atomic_load((const u64*)p, AQ);
}

// W frag index for the register-resident layout (r2-r7 verified).
__device__ __forceinline__ size_t fidx(int np, int k) {
  int s = np >> 5, nl = np & 31;
  int c = k >> 8;
  int kq = (k >> 5) & 7;
  int kfs = (k >> 4) & 1;
  int h = (k >> 3) & 1;
  int e = k & 7;
  int f = c * 2 + kfs;
  return ((size_t)(s * 8 + kq) * 16 + f) * 512 + (h * 32 + nl) * 8 + e;
}

// ---------------- prepass kernels (r2-r7 verified) ----------------

__global__ void k_build_w0f(const float* __restrict__ Whh0, const float* __restrict__ Wih0,
                            const float* __restrict__ fcw, u16* __restrict__ w0f) {
  int np = blockIdx.x;
  int j = np >> 2, gg = np & 3;
  int orig = gg * 1024 + j;
  int tid = threadIdx.x;
  __shared__ float wrow[64];
  if (tid < 64) wrow[tid] = Wih0[orig * 64 + tid];
  __syncthreads();
  for (int k = tid; k < 1024; k += 256) {
    w0f[fidx(np, k)] = f2bf(Whh0[(size_t)orig * 1024 + k]);
    float acc = 0.f;
#pragma unroll
    for (int o = 0; o < 64; ++o) acc += wrow[o] * fcw[o * 1024 + k];
    w0f[fidx(np, 1024 + k)] = f2bf(acc);   // folded Wih0 @ fc_out
  }
}

__global__ void k_build_w1f(const float* __restrict__ Wih1, const float* __restrict__ Whh1,
                            u16* __restrict__ w1f) {
  int np = blockIdx.x;
  int j = np >> 2, gg = np & 3;
  int orig = gg * 1024 + j;
  int tid = threadIdx.x;
  for (int k = tid; k < 1024; k += 256) {
    w1f[fidx(np, k)]        = f2bf(Wih1[(size_t)orig * 1024 + k]);
    w1f[fidx(np, 1024 + k)] = f2bf(Whh1[(size_t)orig * 1024 + k]);
  }
}

__global__ void k_build_bias(const float* bih0, const float* bhh0,
                             const float* bih1, const float* bhh1,
                             const float* Wih0, const float* fcb,
                             float* bias0b, float* bias0x, float* bias1) {
  int np = blockIdx.x * 256 + threadIdx.x;
  if (np >= NGATE) return;
  int j = np >> 2, gg = np & 3;
  int orig = gg * 1024 + j;
  bias0b[np] = bih0[orig] + bhh0[orig];
  bias1[np]  = bih1[orig] + bhh1[orig];
  float acc = 0.f;
#pragma unroll
  for (int o = 0; o < 64; ++o) acc += Wih0[orig * 64 + o] * fcb[o];
  bias0x[np] = acc;   // fc_out bias routed through W_ih0 (valid only t>=1; x(0)=0)
}

__global__ void k_fcwb(const float* __restrict__ fcw, u16* __restrict__ fcwb) {
  int idx = blockIdx.x * 256 + threadIdx.x;  // 65536
  fcwb[idx] = f2bf(fcw[idx]);
}

// writes h0_init -> xg0 slab, h1_init -> xg1 slab
__global__ void k_init(const float* __restrict__ zs, const float* __restrict__ zk,
                       const float* __restrict__ fiw, const float* __restrict__ fib,
                       u16* __restrict__ xg0, u16* __restrict__ xg1) {
  int r = blockIdx.x;
  int tid = threadIdx.x;
  __shared__ float z[256];
  if (tid < 128) z[tid] = zs[r * 128 + tid];
  else           z[tid] = zk[r * 128 + (tid - 128)];
  __syncthreads();
  for (int c = tid; c < 2048; c += 256) {
    float acc = fib[c];
    const float* w = fiw + (size_t)c * 256;
#pragma unroll 8
    for (int k = 0; k < 256; ++k) acc += z[k] * w[k];
    int l = (r >= 256) ? 1 : 0;
    int b = 2 * (r - l * 256) + (c >> 10);
    int h = c & 1023;
    u16 v = f2bf(acc);
    if (l == 0) xg0[(size_t)b * 1024 + h] = v;
    else        xg1[(size_t)b * 1024 + h] = v;
  }
}

// ---------------- main cooperative kernel ----------------

struct Params {
  const u16* w0f;        // frag-ordered, register-resident after prologue
  const u16* w1f;
  const float* bias0b;
  const float* bias0x;
  const float* bias1;
  u16* xg0;              // [512][1024] h0 slab (MALL write-through, single)
  u16* xg1;              // [512][1024] h1 slab
  u16* scr;              // [8 xcd][2 grp][256][2048] per-XCD operand scratch (L2-local)
  const u16* fcwb;       // [64][1024] bf16
  const float* fcb;
  float* out;            // [512][256][64]
  unsigned* igctr;       // init barrier counter
  unsigned* rkg;         // [8 xcd][2 grp] rank counters
  unsigned* gcnt;        // [2] group block totals
  unsigned* sctr;        // [16][NLB] fill-ready counters  (per xcd,grp)
  unsigned* axg;         // [16][NPH] gbar arrival         (per xcd,grp)
  unsigned* rls;         // [16][NPH] gbar release flags   (per xcd,grp)
  unsigned* gctr;        // [2][NPH]  gbar group-combine   (per grp)
};

__global__ __launch_bounds__(NTHR, 2)
void k_lstm(Params p) {
  extern __shared__ char smem[];
  u16* win0 = (u16*)smem;                       // [64][256] bf16, swizzled
  u16* win1 = (u16*)(smem + WIN_BYTES);
  float* pld = (float*)(smem + 2 * WIN_BYTES);  // [8 kq][64 m][32 n] f32
  volatile unsigned* bc = (volatile unsigned*)(smem + 2 * WIN_BYTES + 65536);

  const int blk = blockIdx.x, tid = threadIdx.x;
  const int lane = tid & 63, wave = tid >> 6;   // wave id = kq (K-slice)
  const int x8 = blk & 7;
  const int g = x8 >> 2;                        // batch group 0..1
  const int s = (blk >> 3) * 4 + (x8 & 3);      // gate-slab 0..127 (np 32s..32s+32)
  const int nl = lane & 31, hh = lane >> 5;

  unsigned xcd;
  asm("s_getreg_b32 %0, hwreg(HW_REG_XCC_ID, 0, 32)" : "=s"(xcd));
  xcd &= 7;

  // ---- rank discovery + one global init barrier (agent atomics only) ----
  if (tid == 0) {
    unsigned rg = __hip_atomic_fetch_add(&p.rkg[xcd * 2 + g], 1u, AQ);
    __hip_atomic_fetch_add(&p.gcnt[g], 1u, AQ);
    __hip_atomic_fetch_add(p.igctr, 1u, AQ);
    while (__hip_atomic_load(p.igctr, AQ) < (unsigned)NBLK)
      __builtin_amdgcn_s_sleep(2);
    bc[0] = rg;
    bc[1] = __hip_atomic_load(&p.rkg[xcd * 2 + g], AQ);
    bc[2] = __hip_atomic_load(&p.gcnt[g], AQ);
  }
  __syncthreads();
  const unsigned rg_   = bc[0];   // my rank within (xcd, group)
  const unsigned ng_   = bc[1];   // blocks of my group on this XCD (>=1)
  const unsigned ngrp_ = bc[2];   // total blocks of my group
  const bool lead = (rg_ == 0);
  __syncthreads();

  // ---- load W into registers: zero W fetch for all 512 phases (r2-proven) ----
  bf16x8 w0r[16], w1r[16];
  {
    const u16* W0p = p.w0f + (size_t)(s * 8 + wave) * 8192 + (hh * 32 + nl) * 8;
    const u16* W1p = p.w1f + (size_t)(s * 8 + wave) * 8192 + (hh * 32 + nl) * 8;
#pragma unroll
    for (int f = 0; f < 16; ++f) {
      w0r[f] = *(const bf16x8*)(W0p + f * 512);
      w1r[f] = *(const bf16x8*)(W1p + f * 512);
    }
  }

  // cell assignment: one (row-in-pass, hidden-unit) per lane
  const int cr_ = tid >> 3, cj = tid & 7;
  const int npb = s * 32 + 4 * cj;
  const f32x4 b0 = *(const f32x4*)&p.bias0b[npb];
  const f32x4 bx = *(const f32x4*)&p.bias0x[npb];
  const f32x4 b1 = *(const f32x4*)&p.bias1[npb];
  const int jcol = s * 8 + cj;

  float c0s[4] = {0, 0, 0, 0}, c1s[4] = {0, 0, 0, 0};

  u16* scrg = p.scr + (size_t)(xcd * 2 + g) * 256 * 2048;  // (XCD,group) scratch

  // ---- group-scoped hierarchical barrier (r6/r7-proven, no sc1 fence) ----
  auto gbar = [&](int ph) {
    __syncthreads();   // vmcnt(0) drain -> h write-through stores durable
    if (tid == 0) {
      unsigned* ax = &p.axg[(xcd * 2 + g) * NPH + ph];
      __hip_atomic_fetch_add(ax, 1u, AQ);
      if (lead) {
        while (__hip_atomic_load(ax, AQ) < ng_) __builtin_amdgcn_s_sleep(1);
        unsigned* gc = &p.gctr[g * NPH + ph];
        __hip_atomic_fetch_add(gc, ng_, AQ);
        while (__hip_atomic_load(gc, AQ) < ngrp_) __builtin_amdgcn_s_sleep(1);
        __hip_atomic_store(&p.rls[(xcd * 2 + g) * NPH + ph], 1u, AQ);
      } else {
        while (!__hip_atomic_load(&p.rls[(xcd * 2 + g) * NPH + ph], AQ))
          __builtin_amdgcn_s_sleep(1);
      }
    }
    __syncthreads();
  };

  // XCD-local fill-ready barrier + private-L1 flash (r3/r6/r7-proven cheap)
  auto lbar = [&](int slot) {
    __syncthreads();   // drain fill stores into own L2
    if (tid == 0) {
      unsigned* c = &p.sctr[(xcd * 2 + g) * NLB + slot];
      __hip_atomic_fetch_add(c, 1u, AQ);
      while (__hip_atomic_load(c, AQ) < ng_) __builtin_amdgcn_s_sleep(1);
    }
    __syncthreads();
    asm volatile("buffer_inv sc0\n\ts_waitcnt vmcnt(0)" ::: "memory");
  };

  // HALF-slab fill, BATCHED: 8 independent atomic u64 loads issued before any
  // store -> one exposed MALL latency per 16-row batch (vs 16 serial in r6).
  // Scratch halves persist across phases, so each fill moves only the half
  // just produced (0.5 MB per (xcd,grp)).
  auto fill_half = [&](const u16* src, int off, bool zero) {
    const int half = tid >> 8;          // 0..1: two rows per batch step
    const int c8 = (tid & 255) * 4;     // u64-granule col offset (elems)
    for (int kb = 0; (int)rg_ + kb * (int)ng_ < 256; kb += 16) {
      u64 v[8];
      int rr[8];
#pragma unroll
      for (int it = 0; it < 8; ++it) {
        const int k = kb + it * 2 + half;
        rr[it] = (int)rg_ + k * (int)ng_;
        v[it] = 0;
        if (!zero && rr[it] < 256)
          v[it] = ld_dev64(src + (size_t)(g * 256 + rr[it]) * 1024 + c8);
      }
#pragma unroll
      for (int it = 0; it < 8; ++it)
        if (rr[it] < 256)
          *(u64*)(scrg + (size_t)rr[it] * 2048 + off + c8) = v[it];
    }
  };

  // out(tq) for this block's 2 batch rows; h1(tq) = scratch cols [1024,2048)
  auto out_proj_s = [&](int tq) {
    const int o = tid >> 3, ks = tid & 7;
#pragma unroll
    for (int rr = 0; rr < 2; ++rr) {
      const int rl = 2 * s + rr;
      const u16* hp = scrg + (size_t)rl * 2048 + 1024 + ks * 128;
      const u16* wp = p.fcwb + (size_t)o * 1024 + ks * 128;
      float a = 0.f;
#pragma unroll
      for (int kk = 0; kk < 128; kk += 8) {
        bf16x8 hv = *(const bf16x8*)(hp + kk);
        bf16x8 wv = *(const bf16x8*)(wp + kk);
#pragma unroll
        for (int jj = 0; jj < 8; ++jj)
          a += bf2f(((u16*)&hv)[jj]) * bf2f(((u16*)&wv)[jj]);
      }
      a += __shfl_xor(a, 1);
      a += __shfl_xor(a, 2);
      a += __shfl_xor(a, 4);
      if (ks == 0)
        p.out[((size_t)(g * 256 + rl) * SEQ + tq) * OUTD + o] = a + p.fcb[o];
    }
  };

  // one layer-phase on the XCD scratch (r6-proven 22.2ms core): 4 passes of
  // 64 rows; 8 dbuf XOR-swizzled LDS windows (coalesced 16B L2 reads, staged
  // once per block); 32x32x16 MFMA vs register W; 8-way K reduce via pld;
  // fused cell; single write-through h publish.
  auto phase = [&](bf16x8 (&wr)[16], u16* dst,
                   const f32x4& bb, const f32x4& bxx, bool ubx, float (&cs)[4]) {
#pragma unroll
    for (int pass = 0; pass < 4; ++pass) {
      const u16* Xb = scrg + (size_t)(pass * 64) * 2048;
      f32x16 acc0, acc1;
#pragma unroll
      for (int z = 0; z < 16; ++z) { acc0[z] = 0.f; acc1[z] = 0.f; }

      {  // stage window 0
        const int row = tid >> 3, seg = tid & 7, sw = (row & 7) << 4;
        const u16* src = Xb + (size_t)row * 2048 + seg * 8;
#pragma unroll
        for (int i = 0; i < 4; ++i)
          *(bf16x8*)(win0 + row * 256 + (((seg * 16 + i * 128) ^ sw) >> 1)) =
              *(const bf16x8*)(src + i * 64);
      }
      __syncthreads();
#pragma unroll
      for (int c = 0; c < 8; ++c) {
        u16* cur = (c & 1) ? win1 : win0;
        u16* nxt = (c & 1) ? win0 : win1;
        if (c < 7) {   // stage next window while computing current
          const int row = tid >> 3, seg = tid & 7, sw = (row & 7) << 4;
          const u16* src = Xb + (size_t)row * 2048 + (c + 1) * 256 + seg * 8;
#pragma unroll
          for (int i = 0; i < 4; ++i)
            *(bf16x8*)(nxt + row * 256 + (((seg * 16 + i * 128) ^ sw) >> 1)) =
                *(const bf16x8*)(src + i * 64);
        }
#pragma unroll
        for (int kfs = 0; kfs < 2; ++kfs) {
          const bf16x8 wf = wr[c * 2 + kfs];
          const int bo = wave * 64 + kfs * 32 + hh * 16;
          {
            const int row = nl;
            const bf16x8 a =
                *(const bf16x8*)(cur + row * 256 + ((bo ^ ((row & 7) << 4)) >> 1));
            acc0 = __builtin_amdgcn_mfma_f32_32x32x16_bf16(a, wf, acc0, 0, 0, 0);
          }
          {
            const int row = 32 + nl;
            const bf16x8 a =
                *(const bf16x8*)(cur + row * 256 + ((bo ^ ((row & 7) << 4)) >> 1));
            acc1 = __builtin_amdgcn_mfma_f32_32x32x16_bf16(a, wf, acc1, 0, 0, 0);
          }
        }
        __syncthreads();
      }
      // K-partials to LDS (C/D: col=lane&31, row=(reg&3)+8*(reg>>2)+4*(lane>>5))
#pragma unroll
      for (int r16 = 0; r16 < 16; ++r16) {
        const int row0 = (r16 & 3) + 8 * (r16 >> 2) + 4 * hh;
        pld[(wave * 64 + row0) * 32 + nl] = acc0[r16];
        pld[(wave * 64 + 32 + row0) * 32 + nl] = acc1[r16];
      }
      __syncthreads();
      // reduce 8 partials + fused cell for this lane's (row, hidden unit)
      f32x4 gs = {0.f, 0.f, 0.f, 0.f};
#pragma unroll
      for (int q = 0; q < 8; ++q) {
        const f32x4 v = *(const f32x4*)&pld[(q * 64 + cr_) * 32 + 4 * cj];
        gs[0] += v[0]; gs[1] += v[1]; gs[2] += v[2]; gs[3] += v[3];
      }
      const float gi = gs[0] + bb[0] + (ubx ? bxx[0] : 0.f);
      const float gf = gs[1] + bb[1] + (ubx ? bxx[1] : 0.f);
      const float gg = gs[2] + bb[2] + (ubx ? bxx[2] : 0.f);
      const float go = gs[3] + bb[3] + (ubx ? bxx[3] : 0.f);
      const float iv = sigf(gi), fv = sigf(gf), gv = tanh_fast(gg), ov = sigf(go);
      const float cnew = fv * cs[pass] + iv * gv;
      cs[pass] = cnew;
      const float hnew = ov * tanh_fast(cnew);
      const u16 hv = f2bf(hnew);
      const unsigned other = __shfl_xor((unsigned)hv, 1);
      if (!(tid & 1)) {   // even lane packs (jcol, jcol+1) -> one u32 write-through
        const unsigned pairv = (unsigned)hv | (other << 16);
        st_dev32(dst + (size_t)(g * 256 + pass * 64 + cr_) * 1024 + jcol, pairv);
      }
      __syncthreads();   // pld reuse in next pass
    }
  };

  // prologue: scratch = [h0_init | 0]  (x(0)=0)
  fill_half(p.xg0, 0, false);
  fill_half(nullptr, 1024, true);
  lbar(0);

  for (int t = 0; t < SEQ; ++t) {
    // ---- phase A: operand [h0(t-1) | h1(t-1)] -> h0(t) -> xg0 ----
    if (t > 0) out_proj_s(t - 1);                 // h1(t-1) in scratch hi
    phase(w0r, p.xg0, b0, bx, t > 0, c0s);
    gbar(2 * t);
    // ---- fill B: lo <- h0(t); at t=0 also hi <- h1_init (r5-bugfix case) ----
    fill_half(p.xg0, 0, false);
    if (t == 0) fill_half(p.xg1, 1024, false);
    lbar(2 * t + 1);
    // ---- phase B: operand [h0(t) | h1(t-1)] -> h1(t) -> xg1 ----
    phase(w1r, p.xg1, b1, b1, false, c1s);
    gbar(2 * t + 1);
    // ---- fill A(t+1): hi <- h1(t); lo (h0(t)) already in scratch ----
    if (t + 1 < SEQ) {
      fill_half(p.xg1, 1024, false);
      lbar(2 * t + 2);
    }
  }
  // final out(SEQ-1): h1(255) in xg1, via agent loads
  {
    const int o = tid >> 3, ks = tid & 7;
#pragma unroll
    for (int rr = 0; rr < 2; ++rr) {
      const int r = g * 256 + 2 * s + rr;
      const u16* hp = p.xg1 + (size_t)r * 1024 + ks * 128;
      const u16* wp = p.fcwb + (size_t)o * 1024 + ks * 128;
      float a = 0.f;
      for (int kk = 0; kk < 128; kk += 4) {
        u64 hv = ld_dev64(hp + kk);
        a += bf2f((u16)hv)         * bf2f(wp[kk]);
        a += bf2f((u16)(hv >> 16)) * bf2f(wp[kk + 1]);
        a += bf2f((u16)(hv >> 32)) * bf2f(wp[kk + 2]);
        a += bf2f((u16)(hv >> 48)) * bf2f(wp[kk + 3]);
      }
      a += __shfl_xor(a, 1);
      a += __shfl_xor(a, 2);
      a += __shfl_xor(a, 4);
      if (ks == 0)
        p.out[((size_t)r * SEQ + (SEQ - 1)) * OUTD + o] = a + p.fcb[o];
    }
  }
}

// ---------------- launch ----------------

extern "C" void kernel_launch(void* const* d_in, const int* in_sizes, int n_in,
                              void* d_out, int out_size, void* d_ws, size_t ws_size,
                              hipStream_t stream) {
  const float* zs   = (const float*)d_in[0];
  const float* zk   = (const float*)d_in[1];
  const float* fiw  = (const float*)d_in[2];
  const float* fib  = (const float*)d_in[3];
  const float* Wih0 = (const float*)d_in[4];
  const float* Whh0 = (const float*)d_in[5];
  const float* bih0 = (const float*)d_in[6];
  const float* bhh0 = (const float*)d_in[7];
  const float* Wih1 = (const float*)d_in[8];
  const float* Whh1 = (const float*)d_in[9];
  const float* bih1 = (const float*)d_in[10];
  const float* bhh1 = (const float*)d_in[11];
  const float* fcw  = (const float*)d_in[12];
  const float* fcb  = (const float*)d_in[13];
  float* out = (float*)d_out;

  char* ws = (char*)d_ws;
  size_t off = 0;
  auto alloc = [&](size_t bytes) -> char* {
    char* pp = ws + off;
    off += (bytes + 255) & ~(size_t)255;
    return pp;
  };
  u16* w0f  = (u16*)alloc((size_t)NGATE * 2048 * 2);        // 16 MB
  u16* w1f  = (u16*)alloc((size_t)NGATE * 2048 * 2);        // 16 MB
  u16* xg0  = (u16*)alloc((size_t)HSZ * 2);                 // 1 MB
  u16* xg1  = (u16*)alloc((size_t)HSZ * 2);                 // 1 MB
  u16* scr  = (u16*)alloc((size_t)8 * 2 * 256 * 2048 * 2);  // 16 MB
  u16* fcwb = (u16*)alloc((size_t)OUTD * HID * 2);
  float* bias0b = (float*)alloc(NGATE * 4);
  float* bias0x = (float*)alloc(NGATE * 4);
  float* bias1  = (float*)alloc(NGATE * 4);
  unsigned* igctr = (unsigned*)alloc(256);
  unsigned* rkg   = (unsigned*)alloc(16 * 4);
  unsigned* gcnt  = (unsigned*)alloc(2 * 4);
  unsigned* sctr  = (unsigned*)alloc((size_t)16 * NLB * 4);
  unsigned* axg   = (unsigned*)alloc((size_t)16 * NPH * 4);
  unsigned* rls   = (unsigned*)alloc((size_t)16 * NPH * 4);
  unsigned* gctr  = (unsigned*)alloc((size_t)2 * NPH * 4);

  hipMemsetAsync(igctr, 0, 256, stream);
  hipMemsetAsync(rkg, 0, 16 * 4, stream);
  hipMemsetAsync(gcnt, 0, 2 * 4, stream);
  hipMemsetAsync(sctr, 0, (size_t)16 * NLB * 4, stream);
  hipMemsetAsync(axg, 0, (size_t)16 * NPH * 4, stream);
  hipMemsetAsync(rls, 0, (size_t)16 * NPH * 4, stream);
  hipMemsetAsync(gctr, 0, (size_t)2 * NPH * 4, stream);

  hipLaunchKernelGGL(k_build_w0f, dim3(NGATE), dim3(256), 0, stream, Whh0, Wih0, fcw, w0f);
  hipLaunchKernelGGL(k_build_w1f, dim3(NGATE), dim3(256), 0, stream, Wih1, Whh1, w1f);
  hipLaunchKernelGGL(k_build_bias, dim3(16), dim3(256), 0, stream,
                     bih0, bhh0, bih1, bhh1, Wih0, fcb, bias0b, bias0x, bias1);
  hipLaunchKernelGGL(k_fcwb, dim3(256), dim3(256), 0, stream, fcw, fcwb);
  hipLaunchKernelGGL(k_init, dim3(BATCH), dim3(256), 0, stream, zs, zk, fiw, fib, xg0, xg1);

  Params prm;
  prm.w0f = w0f; prm.w1f = w1f;
  prm.bias0b = bias0b; prm.bias0x = bias0x; prm.bias1 = bias1;
  prm.xg0 = xg0; prm.xg1 = xg1; prm.scr = scr;
  prm.fcwb = fcwb; prm.fcb = fcb; prm.out = out;
  prm.igctr = igctr; prm.rkg = rkg; prm.gcnt = gcnt;
  prm.sctr = sctr; prm.axg = axg; prm.rls = rls; prm.gctr = gctr;

  hipFuncSetAttribute((const void*)k_lstm, hipFuncAttributeMaxDynamicSharedMemorySize, LDS_BYTES);
  void* args[] = { &prm };
  hipLaunchCooperativeKernel((void*)k_lstm, dim3(NBLK), dim3(NTHR), args, LDS_BYTES, stream);
}